// Round 9
// baseline (583.638 us; speedup 1.0000x reference)
//
#include <hip/hip_runtime.h>
#include <math.h>

#define NS_STEPS 30

typedef __attribute__((ext_vector_type(8))) _Float16 half8;
typedef __attribute__((ext_vector_type(4))) _Float16 half4v;
typedef __attribute__((ext_vector_type(8))) short short8;
typedef __attribute__((ext_vector_type(4))) float floatx4;
typedef __attribute__((ext_vector_type(4))) unsigned short ushortx4;

static __device__ inline unsigned short f2bf(float f) {
  union { float f; unsigned u; } v; v.f = f;
  unsigned r = v.u + 0x7fffu + ((v.u >> 16) & 1u);
  return (unsigned short)(r >> 16);
}
static __device__ inline float bf2f(unsigned short h) {
  union { unsigned u; float f; } v; v.u = ((unsigned)h) << 16;
  return v.f;
}

// ============ encoder convs (fused per-channel stats via atomics) ===========
__global__ __launch_bounds__(256) void conv1_k(const float* __restrict__ x,
    const float* __restrict__ w, const float* __restrict__ bias,
    float* __restrict__ out, float* __restrict__ gsum, float* __restrict__ gsq) {
  __shared__ float ws[384];
  __shared__ float ssum[32], ssq[32];
  int tid = threadIdx.x;
  for (int i = tid; i < 384; i += 256) ws[i] = w[i];
  if (tid < 32) { ssum[tid] = 0.f; ssq[tid] = 0.f; }
  __syncthreads();
  int idx = blockIdx.x * 256 + tid;
  int b = idx / 768, r = idx % 768;
  int c = r / 24, h = r % 24;
  const float* xb = x + b * 104 + h * 4;
  const float* wc = ws + c * 12;
  float acc = bias[c];
  #pragma unroll
  for (int kh = 0; kh < 3; kh++)
    #pragma unroll
    for (int kw = 0; kw < 4; kw++)
      acc += xb[kh * 4 + kw] * wc[kh * 4 + kw];
  out[idx] = acc;
  atomicAdd(&ssum[c], acc);
  atomicAdd(&ssq[c], acc * acc);
  __syncthreads();
  if (tid < 32) { atomicAdd(&gsum[tid], ssum[tid]); atomicAdd(&gsq[tid], ssq[tid]); }
}

__global__ __launch_bounds__(256) void conv2_k(const float* __restrict__ in,
    const float* __restrict__ w, const float* __restrict__ bias,
    float* __restrict__ out, float* __restrict__ gsum, float* __restrict__ gsq) {
  __shared__ float ws[2560];
  __shared__ float ssum[16], ssq[16];
  int tid = threadIdx.x;
  for (int i = tid; i < 2560; i += 256) ws[i] = w[i];
  if (tid < 16) { ssum[tid] = 0.f; ssq[tid] = 0.f; }
  __syncthreads();
  int idx = blockIdx.x * 256 + tid;
  int b = idx / 320, r = idx % 320;
  int c = r / 20, h = r % 20;
  const float* ib = in + b * 768 + h;
  const float* wc = ws + c * 160;
  float acc = bias[c];
  for (int i = 0; i < 32; i++)
    #pragma unroll
    for (int kh = 0; kh < 5; kh++)
      acc += ib[i * 24 + kh] * wc[i * 5 + kh];
  out[idx] = acc;
  atomicAdd(&ssum[c], acc);
  atomicAdd(&ssq[c], acc * acc);
  __syncthreads();
  if (tid < 16) { atomicAdd(&gsum[tid], ssum[tid]); atomicAdd(&gsq[tid], ssq[tid]); }
}

__global__ __launch_bounds__(256) void conv3_k(const float* __restrict__ in,
    const float* __restrict__ w, const float* __restrict__ bias,
    float* __restrict__ out, float* __restrict__ gsum, float* __restrict__ gsq) {
  __shared__ float ws[896];
  __shared__ float ssum[8], ssq[8];
  int tid = threadIdx.x;
  for (int i = tid; i < 896; i += 256) ws[i] = w[i];
  if (tid < 8) { ssum[tid] = 0.f; ssq[tid] = 0.f; }
  __syncthreads();
  int idx = blockIdx.x * 256 + tid;
  int b = idx / 112, r = idx % 112;
  int c = r / 14, h = r % 14;
  const float* ib = in + b * 320 + h;
  const float* wc = ws + c * 112;
  float acc = bias[c];
  for (int i = 0; i < 16; i++)
    #pragma unroll
    for (int kh = 0; kh < 7; kh++)
      acc += ib[i * 20 + kh] * wc[i * 7 + kh];
  out[idx] = acc;
  atomicAdd(&ssum[c], acc);
  atomicAdd(&ssq[c], acc * acc);
  __syncthreads();
  if (tid < 8) { atomicAdd(&gsum[tid], ssum[tid]); atomicAdd(&gsq[tid], ssq[tid]); }
}

// ============ decoder tconvs (fused stats where BN follows) ===========
__global__ __launch_bounds__(256) void tconv1_k(const float* __restrict__ in,
    const float* __restrict__ w, const float* __restrict__ bias,
    float* __restrict__ out, float* __restrict__ gsum, float* __restrict__ gsq) {
  __shared__ float ws[896];
  __shared__ float ssum[16], ssq[16];
  int tid = threadIdx.x;
  for (int i = tid; i < 896; i += 256) ws[i] = w[i];
  if (tid < 16) { ssum[tid] = 0.f; ssq[tid] = 0.f; }
  __syncthreads();
  int idx = blockIdx.x * 256 + tid;
  int b = idx / 320, r = idx % 320;
  int c = r / 20, s = r % 20;
  float acc = bias[c];
  for (int o = 0; o < 8; o++)
    #pragma unroll
    for (int kh = 0; kh < 7; kh++) {
      int hs = s - kh;
      if (hs >= 0 && hs < 14)
        acc += in[b * 112 + o * 14 + hs] * ws[o * 112 + c * 7 + kh];
    }
  out[idx] = acc;
  atomicAdd(&ssum[c], acc);
  atomicAdd(&ssq[c], acc * acc);
  __syncthreads();
  if (tid < 16) { atomicAdd(&gsum[tid], ssum[tid]); atomicAdd(&gsq[tid], ssq[tid]); }
}

__global__ __launch_bounds__(256) void tconv2_k(const float* __restrict__ in,
    const float* __restrict__ w, const float* __restrict__ bias,
    float* __restrict__ out, float* __restrict__ gsum, float* __restrict__ gsq) {
  __shared__ float ws[2560];
  __shared__ float ssum[32], ssq[32];
  int tid = threadIdx.x;
  for (int i = tid; i < 2560; i += 256) ws[i] = w[i];
  if (tid < 32) { ssum[tid] = 0.f; ssq[tid] = 0.f; }
  __syncthreads();
  int idx = blockIdx.x * 256 + tid;
  int b = idx / 768, r = idx % 768;
  int c = r / 24, s = r % 24;
  float acc = bias[c];
  for (int o = 0; o < 16; o++)
    #pragma unroll
    for (int kh = 0; kh < 5; kh++) {
      int hs = s - kh;
      if (hs >= 0 && hs < 20)
        acc += in[b * 320 + o * 20 + hs] * ws[o * 160 + c * 5 + kh];
    }
  out[idx] = acc;
  atomicAdd(&ssum[c], acc);
  atomicAdd(&ssq[c], acc * acc);
  __syncthreads();
  if (tid < 32) { atomicAdd(&gsum[tid], ssum[tid]); atomicAdd(&gsq[tid], ssq[tid]); }
}

__global__ __launch_bounds__(256) void tconv3_k(const float* __restrict__ in,
    const float* __restrict__ w, const float* __restrict__ bias,
    float* __restrict__ out) {
  __shared__ float ws[384];
  int tid = threadIdx.x;
  for (int i = tid; i < 384; i += 256) ws[i] = w[i];
  __syncthreads();
  int idx = blockIdx.x * 256 + tid;
  if (idx >= 26624) return;
  int b = idx / 104, r = idx % 104;
  int sh = r / 4, sw = r % 4;
  float acc = bias[0];
  for (int o = 0; o < 32; o++)
    #pragma unroll
    for (int kh = 0; kh < 3; kh++) {
      int hs = sh - kh;
      if (hs >= 0 && hs < 24)
        acc += in[b * 768 + o * 24 + hs] * ws[o * 12 + kh * 4 + sw];
    }
  out[idx] = acc;
}

// ======================= BN apply (stats precomputed) =======================
__global__ __launch_bounds__(256) void bn2d_apply_k(float* __restrict__ x,
    const float* __restrict__ gsum, const float* __restrict__ gsq,
    const float* __restrict__ g, const float* __restrict__ be,
    int C, int HW) {
  int idx = blockIdx.x * 256 + threadIdx.x;
  int c = (idx / HW) % C;
  float cnt = 256.f * (float)HW;
  float m = gsum[c] / cnt;
  float var = gsq[c] / cnt - m * m;
  float v = (x[idx] - m) * rsqrtf(var + 1e-5f) * g[c] + be[c];
  x[idx] = v > 0.f ? v : 0.f;
}

__global__ __launch_bounds__(256) void bn1d_k(float* __restrict__ x,
    const float* __restrict__ g, const float* __restrict__ be, int N) {
  __shared__ float p1[8][32], p2[8][32];
  int t = threadIdx.x;
  int cl = t & 31, rg = t >> 5;
  int c = blockIdx.x * 32 + cl;
  float s = 0.f, s2 = 0.f;
  if (c < N) {
    for (int r = rg * 32; r < rg * 32 + 32; r++) {
      float v = x[r * N + c];
      s += v; s2 += v * v;
    }
  }
  p1[rg][cl] = s; p2[rg][cl] = s2;
  __syncthreads();
  float ts = 0.f, ts2 = 0.f;
  #pragma unroll
  for (int i = 0; i < 8; i++) { ts += p1[i][cl]; ts2 += p2[i][cl]; }
  float m = ts * (1.f / 256.f);
  float var = ts2 * (1.f / 256.f) - m * m;
  float rstd = rsqrtf(var + 1e-5f) * ((c < N) ? g[c] : 1.f);
  float bb = (c < N) ? be[c] : 0.f;
  if (c < N) {
    for (int r = rg * 32; r < rg * 32 + 32; r++) {
      float v = (x[r * N + c] - m) * rstd + bb;
      x[r * N + c] = v > 0.f ? v : 0.f;
    }
  }
}

// ============== one-shot fp32 GEMM (K<=112, N multiple of 64) ===============
__global__ __launch_bounds__(256) void gemm_os_k(const float* __restrict__ A,
    const float* __restrict__ W, const float* __restrict__ bias,
    float* __restrict__ C, int K, int N) {
  __shared__ float As[112 * 68];
  __shared__ float Bs[112 * 68];
  int tid = threadIdx.x;
  int nb = blockIdx.x, mb = blockIdx.y;
  int K16 = K >> 4;
  {
    int row = tid >> 2;
    const float* Ar = A + (size_t)(mb * 64 + row) * K;
    for (int i = 0; i < K16; i++) {
      int j = (tid & 3) + 4 * i;
      float4 v = *(const float4*)(Ar + j * 4);
      int k = j * 4;
      As[k * 68 + row] = v.x;
      As[(k + 1) * 68 + row] = v.y;
      As[(k + 2) * 68 + row] = v.z;
      As[(k + 3) * 68 + row] = v.w;
    }
  }
  {
    int n4 = (tid & 15) * 4;
    for (int i = 0; i < K16; i++) {
      int k = (tid >> 4) + 16 * i;
      float4 v = *(const float4*)(W + (size_t)k * N + nb * 64 + n4);
      *(float4*)(Bs + k * 68 + n4) = v;
    }
  }
  __syncthreads();
  int tm = tid >> 4, tn = tid & 15;
  int m0 = tm * 4, n0 = tn * 4;
  float acc[4][4] = {{0.f}};
  #pragma unroll 8
  for (int kk = 0; kk < K; kk++) {
    float4 a = *(const float4*)(As + kk * 68 + m0);
    float4 b = *(const float4*)(Bs + kk * 68 + n0);
    acc[0][0] += a.x*b.x; acc[0][1] += a.x*b.y; acc[0][2] += a.x*b.z; acc[0][3] += a.x*b.w;
    acc[1][0] += a.y*b.x; acc[1][1] += a.y*b.y; acc[1][2] += a.y*b.z; acc[1][3] += a.y*b.w;
    acc[2][0] += a.z*b.x; acc[2][1] += a.z*b.y; acc[2][2] += a.z*b.z; acc[2][3] += a.z*b.w;
    acc[3][0] += a.w*b.x; acc[3][1] += a.w*b.y; acc[3][2] += a.w*b.z; acc[3][3] += a.w*b.w;
  }
  #pragma unroll
  for (int i = 0; i < 4; i++) {
    int m = mb * 64 + m0 + i;
    #pragma unroll
    for (int j = 0; j < 4; j++) {
      int n = nb * 64 + n0 + j;
      C[(size_t)m * N + n] = acc[i][j] + bias[n];
    }
  }
}

// ============== K-split fp32 GEMM for d4 ===========
__global__ __launch_bounds__(256) void gemm_ks_k(const float* __restrict__ A,
    const float* __restrict__ W, const float* __restrict__ bias,
    float* __restrict__ C) {
  __shared__ float As[64 * 68];
  __shared__ float Bs[64 * 68];
  int tid = threadIdx.x;
  int nb = blockIdx.x, mb = blockIdx.y, kc = blockIdx.z;
  int k0 = kc * 64;
  {
    int row = tid >> 2;
    const float* Ar = A + (size_t)(mb * 64 + row) * 1024 + k0;
    #pragma unroll
    for (int i = 0; i < 4; i++) {
      int j = (tid & 3) + 4 * i;
      float4 v = *(const float4*)(Ar + j * 4);
      int k = j * 4;
      As[k * 68 + row] = v.x;
      As[(k + 1) * 68 + row] = v.y;
      As[(k + 2) * 68 + row] = v.z;
      As[(k + 3) * 68 + row] = v.w;
    }
  }
  {
    int n4 = (tid & 15) * 4;
    int nbase = nb * 64 + n4;
    #pragma unroll
    for (int i = 0; i < 4; i++) {
      int k = (tid >> 4) + 16 * i;
      const float* Wr = W + (size_t)(k0 + k) * 112;
      float4 v;
      v.x = (nbase     < 112) ? Wr[nbase]     : 0.f;
      v.y = (nbase + 1 < 112) ? Wr[nbase + 1] : 0.f;
      v.z = (nbase + 2 < 112) ? Wr[nbase + 2] : 0.f;
      v.w = (nbase + 3 < 112) ? Wr[nbase + 3] : 0.f;
      *(float4*)(Bs + k * 68 + n4) = v;
    }
  }
  __syncthreads();
  int tm = tid >> 4, tn = tid & 15;
  int m0 = tm * 4, n0 = tn * 4;
  float acc[4][4] = {{0.f}};
  #pragma unroll 8
  for (int kk = 0; kk < 64; kk++) {
    float4 a = *(const float4*)(As + kk * 68 + m0);
    float4 b = *(const float4*)(Bs + kk * 68 + n0);
    acc[0][0] += a.x*b.x; acc[0][1] += a.x*b.y; acc[0][2] += a.x*b.z; acc[0][3] += a.x*b.w;
    acc[1][0] += a.y*b.x; acc[1][1] += a.y*b.y; acc[1][2] += a.y*b.z; acc[1][3] += a.y*b.w;
    acc[2][0] += a.z*b.x; acc[2][1] += a.z*b.y; acc[2][2] += a.z*b.z; acc[2][3] += a.z*b.w;
    acc[3][0] += a.w*b.x; acc[3][1] += a.w*b.y; acc[3][2] += a.w*b.z; acc[3][3] += a.w*b.w;
  }
  #pragma unroll
  for (int i = 0; i < 4; i++) {
    int m = mb * 64 + m0 + i;
    #pragma unroll
    for (int j = 0; j < 4; j++) {
      int n = nb * 64 + n0 + j;
      if (n < 112) {
        float v = acc[i][j] + (kc == 0 ? bias[n] : 0.f);
        atomicAdd(&C[m * 112 + n], v);
      }
    }
  }
}

// ====================== pack A to bf16 hi/lo (once) =========================
__global__ __launch_bounds__(256) void pack_a_k(const float* __restrict__ in,
    short* __restrict__ ah, short* __restrict__ al) {
  int i = blockIdx.x * 256 + threadIdx.x;   // x4 floats
  float4 v = ((const float4*)in)[i];
  ushortx4 h, lo;
  float av[4] = {v.x, v.y, v.z, v.w};
  #pragma unroll
  for (int j = 0; j < 4; j++) {
    unsigned short hh = f2bf(av[j]);
    ((unsigned short*)&h)[j] = hh;
    ((unsigned short*)&lo)[j] = f2bf(av[j] - bf2f(hh));
  }
  ((ushortx4*)ah)[i] = h;
  ((ushortx4*)al)[i] = lo;
}

// ========= fused head GEMMs, compensated-bf16 MFMA, pipelined v2 ============
// Round-8 fixes: pre-packed A (global short8 frags, no in-loop A convert),
// double-buffered W LDS w/ 1-chunk prefetch (one barrier/chunk), conflict-free
// W transpose: thread (kr=tid>>3, wc=tid&7) writes Wh[(wc+8i)*40+kr] — lane
// banks {0,20,8,28,16,4,24,12}×4sub = all 32 banks at 2-way (free, m136).
// Row stride 40 shorts = 80 B keeps b128 fragment reads 16B-aligned.
struct HeadArgs {
  const float* W[7];
  const float* b[7];
  float* dst[7];
  int off[8];
  int ldw[7];
  int op[7];
};

__global__ __launch_bounds__(256) void heads_mfma_k(
    const short* __restrict__ Ahg, const short* __restrict__ Alg, HeadArgs ha) {
  __shared__ short Wh[2][64 * 40], Wl[2][64 * 40];
  int tid = threadIdx.x;
  int nb = blockIdx.x, mb = blockIdx.y;
  int r = 0;
  int gc = nb * 64;
  while (gc >= ha.off[r + 1]) r++;
  const float* Wp = ha.W[r];
  const float* bias = ha.b[r];
  float* dst = ha.dst[r];
  int ldw = ha.ldw[r];
  int op = ha.op[r];
  int nloc0 = gc - ha.off[r];

  int w = tid >> 6, l = tid & 63;
  int lane16 = l & 15, quad = l >> 4;
  int kr = tid >> 3;   // 0..31
  int wc = tid & 7;    // 0..7
  const float* Wcol = Wp + nloc0 + wc;

  const short* Ah0 = Ahg + (mb * 64 + lane16) * 1024 + quad * 8;
  const short* Al0 = Alg + (mb * 64 + lane16) * 1024 + quad * 8;

  const floatx4 zero4 = {0.f, 0.f, 0.f, 0.f};
  floatx4 acc[4] = {zero4, zero4, zero4, zero4};

  // prologue: W chunk 0 -> LDS[0]; prefetch A frags chunk 0
  {
    float wv[8];
    #pragma unroll
    for (int i = 0; i < 8; i++) wv[i] = Wcol[kr * ldw + 8 * i];
    #pragma unroll
    for (int i = 0; i < 8; i++) {
      unsigned short h = f2bf(wv[i]);
      Wh[0][(wc + 8 * i) * 40 + kr] = (short)h;
      Wl[0][(wc + 8 * i) * 40 + kr] = (short)f2bf(wv[i] - bf2f(h));
    }
  }
  short8 pah[4], pal[4];
  #pragma unroll
  for (int mt = 0; mt < 4; mt++) {
    pah[mt] = *(const short8*)(Ah0 + mt * 16384);
    pal[mt] = *(const short8*)(Al0 + mt * 16384);
  }
  __syncthreads();

  for (int chunk = 0; chunk < 32; ++chunk) {
    int cur = chunk & 1;
    float wvn[8];
    short8 nah[4], nal[4];
    if (chunk < 31) {
      int k0 = (chunk + 1) * 32;
      #pragma unroll
      for (int i = 0; i < 8; i++) wvn[i] = Wcol[(k0 + kr) * ldw + 8 * i];
      #pragma unroll
      for (int mt = 0; mt < 4; mt++) {
        nah[mt] = *(const short8*)(Ah0 + mt * 16384 + k0);
        nal[mt] = *(const short8*)(Al0 + mt * 16384 + k0);
      }
    }
    short8 bh = *(short8*)(&Wh[cur][(w * 16 + lane16) * 40 + quad * 8]);
    short8 bl = *(short8*)(&Wl[cur][(w * 16 + lane16) * 40 + quad * 8]);
    #pragma unroll
    for (int mt = 0; mt < 4; mt++) {
      acc[mt] = __builtin_amdgcn_mfma_f32_16x16x32_bf16(pah[mt], bh, acc[mt], 0, 0, 0);
      acc[mt] = __builtin_amdgcn_mfma_f32_16x16x32_bf16(pah[mt], bl, acc[mt], 0, 0, 0);
      acc[mt] = __builtin_amdgcn_mfma_f32_16x16x32_bf16(pal[mt], bh, acc[mt], 0, 0, 0);
    }
    if (chunk < 31) {
      int nxt = cur ^ 1;
      #pragma unroll
      for (int i = 0; i < 8; i++) {
        unsigned short h = f2bf(wvn[i]);
        Wh[nxt][(wc + 8 * i) * 40 + kr] = (short)h;
        Wl[nxt][(wc + 8 * i) * 40 + kr] = (short)f2bf(wvn[i] - bf2f(h));
      }
      #pragma unroll
      for (int mt = 0; mt < 4; mt++) { pah[mt] = nah[mt]; pal[mt] = nal[mt]; }
    }
    __syncthreads();
  }
  int n = nloc0 + w * 16 + lane16;
  float bv = bias[n];
  #pragma unroll
  for (int mt = 0; mt < 4; mt++) {
    #pragma unroll
    for (int i = 0; i < 4; i++) {
      int m = mb * 64 + mt * 16 + quad * 4 + i;
      float v = acc[mt][i] + bv;
      if (op == 1) v = tanhf(v);
      dst[m * ldw + n] = v;
    }
  }
}

// ============ Newton-Schulz: fully compensated f16 MFMA =====================
__global__ __launch_bounds__(64) void ns_f16split_k(const float* __restrict__ q,
                                                    float* __restrict__ amat) {
  __align__(16) __shared__ _Float16 arena[12288];
  int l = threadIdx.x;
  int lane16 = l & 15, quad = l >> 4;
  _Float16* Ah_cm = arena;          // [32][72]
  _Float16* Al_cm = arena + 2304;   // [32][72]
  _Float16* Mh_cm = arena + 4608;   // [32][40]
  _Float16* Ml_cm = arena + 5888;   // [32][40]
  _Float16* Ah_rm = arena + 7168;   // [64][40]
  _Float16* Al_rm = arena + 9728;   // [64][40]
  float* Afin = (float*)arena;      // [64][36]

  const float* g = q + (size_t)blockIdx.x * 2048;
  float* o = amat + (size_t)blockIdx.x * 2048;

  float vals[32];
  float ss = 0.f;
  #pragma unroll
  for (int j = 0; j < 8; j++) {
    float4 v = *(const float4*)(g + l * 32 + j * 4);
    vals[4*j] = v.x; vals[4*j+1] = v.y; vals[4*j+2] = v.z; vals[4*j+3] = v.w;
    ss += v.x*v.x + v.y*v.y + v.z*v.z + v.w*v.w;
  }
  #pragma unroll
  for (int off = 32; off > 0; off >>= 1) ss += __shfl_xor(ss, off);
  float rn = rsqrtf(ss);
  #pragma unroll
  for (int i = 0; i < 32; i++) vals[i] *= rn;
  #pragma unroll
  for (int j = 0; j < 8; j++) {
    half4v ph, pl;
    #pragma unroll
    for (int r = 0; r < 4; r++) {
      float v = vals[4*j + r];
      _Float16 h = (_Float16)v;
      _Float16 lo = (_Float16)(v - (float)h);
      ph[r] = h; pl[r] = lo;
    }
    *(half4v*)(Ah_rm + l * 40 + j * 4) = ph;
    *(half4v*)(Al_rm + l * 40 + j * 4) = pl;
  }
  #pragma unroll
  for (int i = 0; i < 32; i++) {
    float v = vals[i];
    _Float16 h = (_Float16)v;
    Ah_cm[i * 72 + l] = h;
    Al_cm[i * 72 + l] = (_Float16)(v - (float)h);
  }
  __syncthreads();

  const floatx4 zero4 = {0.f, 0.f, 0.f, 0.f};
  for (int s = 0; s < NS_STEPS; s++) {
    bool last = (s == NS_STEPS - 1);
    half8 fah[2][2], fal[2][2];
    #pragma unroll
    for (int ti = 0; ti < 2; ti++)
      #pragma unroll
      for (int c = 0; c < 2; c++) {
        fah[ti][c] = *(half8*)(Ah_cm + (ti * 16 + lane16) * 72 + c * 32 + quad * 8);
        fal[ti][c] = *(half8*)(Al_cm + (ti * 16 + lane16) * 72 + c * 32 + quad * 8);
      }
    floatx4 gf[2][2] = {{zero4, zero4}, {zero4, zero4}};
    #pragma unroll
    for (int ti = 0; ti < 2; ti++)
      #pragma unroll
      for (int tj = 0; tj < 2; tj++)
        #pragma unroll
        for (int c = 0; c < 2; c++) {
          gf[ti][tj] = __builtin_amdgcn_mfma_f32_16x16x32_f16(
              fah[ti][c], fah[tj][c], gf[ti][tj], 0, 0, 0);
          gf[ti][tj] = __builtin_amdgcn_mfma_f32_16x16x32_f16(
              fah[ti][c], fal[tj][c], gf[ti][tj], 0, 0, 0);
          gf[ti][tj] = __builtin_amdgcn_mfma_f32_16x16x32_f16(
              fal[ti][c], fah[tj][c], gf[ti][tj], 0, 0, 0);
        }
    #pragma unroll
    for (int ti = 0; ti < 2; ti++)
      #pragma unroll
      for (int tj = 0; tj < 2; tj++) {
        int col = tj * 16 + lane16;
        int row0 = ti * 16 + quad * 4;
        half4v ph, pl;
        #pragma unroll
        for (int r = 0; r < 4; r++) {
          float m = ((row0 + r) == col ? 1.5f : 0.f) - 0.5f * gf[ti][tj][r];
          _Float16 h = (_Float16)m;
          ph[r] = h; pl[r] = (_Float16)(m - (float)h);
        }
        *(half4v*)(Mh_cm + col * 40 + row0) = ph;
        *(half4v*)(Ml_cm + col * 40 + row0) = pl;
      }
    __syncthreads();
    half8 fmh[2], fml[2], fbh[4], fbl[4];
    #pragma unroll
    for (int ti = 0; ti < 2; ti++) {
      fmh[ti] = *(half8*)(Mh_cm + (ti * 16 + lane16) * 40 + quad * 8);
      fml[ti] = *(half8*)(Ml_cm + (ti * 16 + lane16) * 40 + quad * 8);
    }
    #pragma unroll
    for (int tj = 0; tj < 4; tj++) {
      fbh[tj] = *(half8*)(Ah_rm + (tj * 16 + lane16) * 40 + quad * 8);
      fbl[tj] = *(half8*)(Al_rm + (tj * 16 + lane16) * 40 + quad * 8);
    }
    floatx4 df[2][4];
    #pragma unroll
    for (int ti = 0; ti < 2; ti++)
      #pragma unroll
      for (int tj = 0; tj < 4; tj++) {
        df[ti][tj] = __builtin_amdgcn_mfma_f32_16x16x32_f16(
            fmh[ti], fbh[tj], zero4, 0, 0, 0);
        df[ti][tj] = __builtin_amdgcn_mfma_f32_16x16x32_f16(
            fmh[ti], fbl[tj], df[ti][tj], 0, 0, 0);
        df[ti][tj] = __builtin_amdgcn_mfma_f32_16x16x32_f16(
            fml[ti], fbh[tj], df[ti][tj], 0, 0, 0);
      }
    __syncthreads();
    if (!last) {
      #pragma unroll
      for (int ti = 0; ti < 2; ti++)
        #pragma unroll
        for (int tj = 0; tj < 4; tj++) {
          int z = tj * 16 + lane16;
          int d0 = ti * 16 + quad * 4;
          half4v ph, pl;
          #pragma unroll
          for (int r = 0; r < 4; r++) {
            float v = df[ti][tj][r];
            _Float16 h = (_Float16)v;
            ph[r] = h; pl[r] = (_Float16)(v - (float)h);
          }
          *(half4v*)(Ah_rm + z * 40 + d0) = ph;
          *(half4v*)(Al_rm + z * 40 + d0) = pl;
          #pragma unroll
          for (int r = 0; r < 4; r++) {
            Ah_cm[(d0 + r) * 72 + z] = ph[r];
            Al_cm[(d0 + r) * 72 + z] = pl[r];
          }
        }
    } else {
      #pragma unroll
      for (int ti = 0; ti < 2; ti++)
        #pragma unroll
        for (int tj = 0; tj < 4; tj++) {
          int z = tj * 16 + lane16;
          int d0 = ti * 16 + quad * 4;
          float4 v;
          v.x = df[ti][tj][0]; v.y = df[ti][tj][1];
          v.z = df[ti][tj][2]; v.w = df[ti][tj][3];
          *(float4*)(Afin + z * 36 + d0) = v;
        }
    }
    __syncthreads();
  }
  #pragma unroll
  for (int j = 0; j < 8; j++) {
    int f = j * 256 + l * 4;
    int z = f >> 5, d = f & 31;
    float4 v = *(const float4*)(Afin + z * 36 + d);
    *(float4*)(o + f) = v;
  }
}

// ======================= Sylvester flow (K=4 steps) =======================
__global__ __launch_bounds__(64) void flow_k(const float* __restrict__ amat,
    const float* __restrict__ fd, const float* __restrict__ dg1,
    const float* __restrict__ dg2, const float* __restrict__ ab,
    const float* __restrict__ eps, float* __restrict__ dout) {
  __shared__ float Ps[32][64];
  __shared__ float wsh[32], tsh[32], ush[32];
  int b = blockIdx.x, l = threadIdx.x;
  float mv  = dout[26624 + b * 64 + l];
  float lvv = dout[43008 + b * 64 + l];
  float z0 = mv + eps[b * 64 + l] * expf(0.5f * lvv);
  dout[59648 + b * 64 + l] = z0;
  float zv = z0;
  float ldj = 0.f;
  float q[32];
  for (int k = 0; k < 4; k++) {
    const float4* qrow = (const float4*)(amat + (size_t)(b * 4 + k) * 2048 + l * 32);
    #pragma unroll
    for (int j = 0; j < 8; j++) {
      float4 v = qrow[j];
      q[4*j] = v.x; q[4*j+1] = v.y; q[4*j+2] = v.z; q[4*j+3] = v.w;
    }
    #pragma unroll
    for (int d = 0; d < 32; d++) Ps[d][l] = zv * q[d];
    __syncthreads();
    if (l < 32) {
      const float4* pr = (const float4*)Ps[l];
      float s = 0.f;
      #pragma unroll
      for (int j = 0; j < 16; j++) {
        float4 v = pr[j];
        s += v.x + v.y + v.z + v.w;
      }
      wsh[l] = s;
    }
    __syncthreads();
    if (l < 32) {
      int e = l;
      float acc = ab[b * 128 + e * 4 + k] + wsh[e] * dg2[b * 128 + e * 4 + k];
      for (int d = e + 1; d < 32; d++)
        acc += wsh[d] * fd[b * 4096 + d * 128 + e * 4 + k];
      float tt = tanhf(acc);
      tsh[e] = tt;
      float dd = (1.f - tt * tt) * (dg1[b*128 + e*4 + k] * dg2[b*128 + e*4 + k]) + 1.f;
      ldj += logf(fabsf(dd));
    }
    __syncthreads();
    if (l < 32) {
      int d = l;
      float acc = tsh[d] * dg1[b * 128 + d * 4 + k];
      for (int e = d + 1; e < 32; e++)
        acc += fd[b * 4096 + d * 128 + e * 4 + k] * tsh[e];
      ush[d] = acc;
    }
    __syncthreads();
    #pragma unroll
    for (int d = 0; d < 32; d++) zv += q[d] * ush[d];
    __syncthreads();
  }
  dout[76032 + b * 64 + l] = zv;
  for (int off = 16; off > 0; off >>= 1) ldj += __shfl_down(ldj, off, 32);
  if (l == 0) dout[59392 + b] = ldj;
}

// ======================= host launch =======================
extern "C" void kernel_launch(void* const* d_in, const int* in_sizes, int n_in,
                              void* d_out, int out_size, void* d_ws, size_t ws_size,
                              hipStream_t stream) {
  (void)in_sizes; (void)n_in; (void)out_size; (void)ws_size;
  const float* x     = (const float*)d_in[0];
  const float* eps   = (const float*)d_in[1];
  const float* cw1   = (const float*)d_in[2];
  const float* cb1   = (const float*)d_in[3];
  const float* g1    = (const float*)d_in[4];
  const float* be1   = (const float*)d_in[5];
  const float* cw2   = (const float*)d_in[6];
  const float* cb2   = (const float*)d_in[7];
  const float* g2    = (const float*)d_in[8];
  const float* be2   = (const float*)d_in[9];
  const float* cw3   = (const float*)d_in[10];
  const float* cb3   = (const float*)d_in[11];
  const float* g3    = (const float*)d_in[12];
  const float* be3   = (const float*)d_in[13];
  const float* d1_w  = (const float*)d_in[14];
  const float* d1_b  = (const float*)d_in[15];
  const float* bn1_g = (const float*)d_in[16];
  const float* bn1_b = (const float*)d_in[17];
  const float* mu_w  = (const float*)d_in[18];
  const float* mu_b  = (const float*)d_in[19];
  const float* lv_w  = (const float*)d_in[20];
  const float* lv_b  = (const float*)d_in[21];
  const float* ad_w  = (const float*)d_in[22];
  const float* ad_b  = (const float*)d_in[23];
  const float* adg1_w= (const float*)d_in[24];
  const float* adg1_b= (const float*)d_in[25];
  const float* adg2_w= (const float*)d_in[26];
  const float* adg2_b= (const float*)d_in[27];
  const float* aq_w  = (const float*)d_in[28];
  const float* aq_b  = (const float*)d_in[29];
  const float* ab_w  = (const float*)d_in[30];
  const float* ab_b  = (const float*)d_in[31];
  const float* d3_w  = (const float*)d_in[32];
  const float* d3_b  = (const float*)d_in[33];
  const float* bn3_g = (const float*)d_in[34];
  const float* bn3_b = (const float*)d_in[35];
  const float* d4_w  = (const float*)d_in[36];
  const float* d4_b  = (const float*)d_in[37];
  const float* bn4_g = (const float*)d_in[38];
  const float* bn4_b = (const float*)d_in[39];
  const float* tw1   = (const float*)d_in[40];
  const float* tb1   = (const float*)d_in[41];
  const float* tg1   = (const float*)d_in[42];
  const float* tbe1  = (const float*)d_in[43];
  const float* tw2   = (const float*)d_in[44];
  const float* tb2   = (const float*)d_in[45];
  const float* tg2   = (const float*)d_in[46];
  const float* tbe2  = (const float*)d_in[47];
  const float* tw3   = (const float*)d_in[48];
  const float* tb3   = (const float*)d_in[49];

  float* out = (float*)d_out;
  float* wsf = (float*)d_ws;
  float* h1   = wsf;                 // 196608  (later: packed A, then t2)
  float* h2   = wsf + 196608;        // 81920   (packed A tail, then t1)
  float* h3   = wsf + 278528;        // 28672   (later: dec2)
  float* out1 = wsf + 307200;        // 262144  (later: dec1)
  float* fd   = wsf + 569344;        // 1048576
  float* dg1  = wsf + 1617920;       // 32768
  float* dg2  = wsf + 1650688;       // 32768
  float* qb   = wsf + 1683456;       // 2097152
  float* ab   = wsf + 3780608;       // 32768
  float* amat = wsf + 3813376;       // 2097152
  float* st   = wsf + 5910528;       // 208 floats of BN stats
  float* dec1 = out1;
  float* dec2 = h3;
  float* t1   = h2;
  float* t2   = h1;
  short* Ahg  = (short*)h1;              // 262144 shorts
  short* Alg  = (short*)(h1 + 131072);   // 262144 shorts (ends at h1+262144 < h3)

  float* L1s = st;       float* L1q = st + 32;
  float* L2s = st + 64;  float* L2q = st + 80;
  float* L3s = st + 96;  float* L3q = st + 104;
  float* T1s = st + 112; float* T1q = st + 128;
  float* T2s = st + 144; float* T2q = st + 176;

  float* mean_o = out + 26624;
  float* lv_o   = out + 43008;
  float* z_o    = out + 76032;

  hipMemsetAsync(st, 0, 208 * sizeof(float), stream);

  // ---------------- encoder ----------------
  conv1_k<<<768, 256, 0, stream>>>(x, cw1, cb1, h1, L1s, L1q);
  bn2d_apply_k<<<768, 256, 0, stream>>>(h1, L1s, L1q, g1, be1, 32, 24);
  conv2_k<<<320, 256, 0, stream>>>(h1, cw2, cb2, h2, L2s, L2q);
  bn2d_apply_k<<<320, 256, 0, stream>>>(h2, L2s, L2q, g2, be2, 16, 20);
  conv3_k<<<112, 256, 0, stream>>>(h2, cw3, cb3, h3, L3s, L3q);
  bn2d_apply_k<<<112, 256, 0, stream>>>(h3, L3s, L3q, g3, be3, 8, 14);

  gemm_os_k<<<dim3(16, 4), 256, 0, stream>>>(h3, d1_w, d1_b, out1, 112, 1024);
  bn1d_k<<<32, 256, 0, stream>>>(out1, bn1_g, bn1_b, 1024);

  // ---------------- fused heads (MFMA, pipelined) ----------------
  pack_a_k<<<256, 256, 0, stream>>>(out1, Ahg, Alg);
  HeadArgs ha;
  ha.W[0] = mu_w;   ha.b[0] = mu_b;   ha.dst[0] = mean_o; ha.ldw[0] = 64;   ha.op[0] = 0;
  ha.W[1] = lv_w;   ha.b[1] = lv_b;   ha.dst[1] = lv_o;   ha.ldw[1] = 64;   ha.op[1] = 0;
  ha.W[2] = ad_w;   ha.b[2] = ad_b;   ha.dst[2] = fd;     ha.ldw[2] = 4096; ha.op[2] = 0;
  ha.W[3] = adg1_w; ha.b[3] = adg1_b; ha.dst[3] = dg1;    ha.ldw[3] = 128;  ha.op[3] = 1;
  ha.W[4] = adg2_w; ha.b[4] = adg2_b; ha.dst[4] = dg2;    ha.ldw[4] = 128;  ha.op[4] = 1;
  ha.W[5] = aq_w;   ha.b[5] = aq_b;   ha.dst[5] = qb;     ha.ldw[5] = 8192; ha.op[5] = 0;
  ha.W[6] = ab_w;   ha.b[6] = ab_b;   ha.dst[6] = ab;     ha.ldw[6] = 128;  ha.op[6] = 0;
  ha.off[0] = 0;    ha.off[1] = 64;   ha.off[2] = 128;  ha.off[3] = 4224;
  ha.off[4] = 4352; ha.off[5] = 4480; ha.off[6] = 12672; ha.off[7] = 12800;
  heads_mfma_k<<<dim3(200, 4), 256, 0, stream>>>(Ahg, Alg, ha);

  // ---------------- orthogonalization + flow ----------------
  ns_f16split_k<<<1024, 64, 0, stream>>>(qb, amat);
  flow_k<<<256, 64, 0, stream>>>(amat, fd, dg1, dg2, ab, eps, out);

  // ---------------- decoder ----------------
  gemm_os_k<<<dim3(16, 4), 256, 0, stream>>>(z_o, d3_w, d3_b, dec1, 64, 1024);
  bn1d_k<<<32, 256, 0, stream>>>(dec1, bn3_g, bn3_b, 1024);
  hipMemsetAsync(dec2, 0, 28672 * sizeof(float), stream);
  gemm_ks_k<<<dim3(2, 4, 16), 256, 0, stream>>>(dec1, d4_w, d4_b, dec2);
  bn1d_k<<<4, 256, 0, stream>>>(dec2, bn4_g, bn4_b, 112);

  tconv1_k<<<320, 256, 0, stream>>>(dec2, tw1, tb1, t1, T1s, T1q);
  bn2d_apply_k<<<320, 256, 0, stream>>>(t1, T1s, T1q, tg1, tbe1, 16, 20);
  tconv2_k<<<768, 256, 0, stream>>>(t1, tw2, tb2, t2, T2s, T2q);
  bn2d_apply_k<<<768, 256, 0, stream>>>(t2, T2s, T2q, tg2, tbe2, 32, 24);
  tconv3_k<<<104, 256, 0, stream>>>(t2, tw3, tb3, out);
}